// Round 4
// baseline (443.885 us; speedup 1.0000x reference)
//
#include <hip/hip_runtime.h>
#include <hip/hip_bf16.h>
#include <cstdint>

// LongcatFlashTopkRouter R8.
// classify = HS @ W^T (fp32 via split-bf16 3-product MFMA 32x32x16), then
// softmax -> +bias -> top-8 -> gather unbiased scores * 1.5.
// Outputs (flat f32): classify [16384*256] | weights [16384*8] | indices [16384*8]
//
// R8 changes vs R7 (426.1 us):
//  - Single-kernel fusion: grid 256, block = M=64 x E=256 x K=4096 (32 chunks).
//    No k-half partials -> no p1 (16MB w + 16MB r), no classify re-read/rewrite
//    (32MB + 16MB), no topk kernel launch. Epilogue: acc -> LDS (reuse Ash's
//    64KB), coalesced classify store, in-block softmax/top-8 (one wave per 8
//    rows, same verified per-token algorithm).
//  - Two accumulator sets (chunks 0-15 -> accA, 16-31 -> accB, added at
//    epilogue) preserve R7's exact summation structure -> absmax unchanged.
//  - Same staging shard, same frag-major LDS layout, same B ring (gs 0..255),
//    same T4 barrier (lgkmcnt-only) + T5 setprio.

typedef __attribute__((ext_vector_type(8))) short short8;    // 8 bf16 MFMA A/B frag
typedef __attribute__((ext_vector_type(16))) float f32x16;   // 32x32 MFMA C/D frag

#define T_TOK  16384
#define DIM    4096
#define NE     256
#define TOPK_N 8

__device__ __forceinline__ float bf2f_u(unsigned short h) {
  return __uint_as_float(((unsigned int)h) << 16);
}
// pack 2 floats -> 2 bf16 RNE in one u32 (f0 low, f1 high); v_cvt_pk_bf16_f32 on gfx950
__device__ __forceinline__ unsigned cvt_pk2(float f0, float f1) {
  __hip_bfloat162 h2 = __float22bfloat162_rn(float2{f0, f1});
  unsigned u;
  __builtin_memcpy(&u, &h2, 4);
  return u;
}
// split 8 floats -> hi uint4 + lo uint4 (Markidis residual, exact)
__device__ __forceinline__ void split8(const float* f, uint4& hv, uint4& lv) {
  unsigned h[4], l[4];
#pragma unroll
  for (int c = 0; c < 4; ++c) {
    float a = f[2 * c], b = f[2 * c + 1];
    h[c] = cvt_pk2(a, b);
    float ra = a - bf2f_u((unsigned short)(h[c] & 0xffffu));
    float rb = b - bf2f_u((unsigned short)(h[c] >> 16));
    l[c] = cvt_pk2(ra, rb);
  }
  hv = uint4{h[0], h[1], h[2], h[3]};
  lv = uint4{l[0], l[1], l[2], l[3]};
}

// ---- pack W fp32 -> fragment-major hi/lo bf16 for 32x32x16 B-frags ---------------
// Wp[((nt*256 + s)*64 + h*32 + col)*8 + j] = W[nt*32+col][s*16 + h*8 + j]
__global__ __launch_bounds__(256) void convert_w_kernel(
    const float* __restrict__ W,
    unsigned short* __restrict__ Whp,
    unsigned short* __restrict__ Wlp) {
  const int t = blockIdx.x * 256 + threadIdx.x;   // 131072 threads
  const int e = t >> 9, k8 = t & 511;
  const int nt = e >> 5, col = e & 31;
  const int s = k8 >> 1, h = k8 & 1;
  const float* src = W + (size_t)e * DIM + k8 * 8;
  float f[8];
  *(float4*)(f)     = *(const float4*)src;
  *(float4*)(f + 4) = *(const float4*)(src + 4);
  uint4 hv, lv;
  split8(f, hv, lv);
  const size_t dst = ((size_t)(nt * 256 + s) * 64 + h * 32 + col) * 8;
  *(uint4*)(Whp + dst) = hv;
  *(uint4*)(Wlp + dst) = lv;
}

// ---- fused GEMM + softmax/top-8 --------------------------------------------------
__device__ __forceinline__ f32x16 mfma32(short8 a, short8 b, f32x16 c) {
  return __builtin_amdgcn_mfma_f32_32x32x16_bf16(a, b, c, 0, 0, 0);
}

__global__ __launch_bounds__(512, 2) void router_fused(
    const float* __restrict__ A,
    const unsigned short* __restrict__ Whp,
    const unsigned short* __restrict__ Wlp,
    const float* __restrict__ bias,
    float* __restrict__ classify,
    float* __restrict__ wOut, float* __restrict__ iOut) {
  // [buf][hilo][mt][ks(8)][lane][8] = 64 KB; reused as Cl[64][256] f32 in epilogue
  __shared__ __align__(16) unsigned short Ash[2][2][2][8][64][8];

  const int tid  = threadIdx.x;
  const int w    = tid >> 6, l = tid & 63;   // 8 waves; wave w owns nt = w
  const int band = blockIdx.x;               // 0..255, 64 rows each

  // staging: thread covers row = tid>>3, k-window (tid&7)*16 .. +16 (1 ks step)
  const int srow = tid >> 3, kg = tid & 7;
  const int smt = srow >> 5, sr = srow & 31;
  const float* ap = A + (size_t)(band * 64 + srow) * DIM + kg * 16;

  // B packed pointers: wave w owns nt = w; full K (256 k-steps)
  const unsigned short* ph = Whp + (size_t)w * 256 * 512 + (size_t)l * 8;
  const unsigned short* pl = Wlp + (size_t)w * 256 * 512 + (size_t)l * 8;

  f32x16 accA0 = {}, accA1 = {}, accB0 = {}, accB1 = {};
  float ar[16];

  // prologue: chunk 0 -> LDS buf0; chunk 1 -> regs; B depth-2 prefetch
#pragma unroll
  for (int i = 0; i < 4; ++i)
    *(float4*)(ar + i * 4) = *(const float4*)(ap + i * 4);
  {
    uint4 hv0, lv0, hv1, lv1;
    split8(ar,     hv0, lv0);
    split8(ar + 8, hv1, lv1);
    *(uint4*)&Ash[0][0][smt][kg][ 0 + sr][0] = hv0;
    *(uint4*)&Ash[0][0][smt][kg][32 + sr][0] = hv1;
    *(uint4*)&Ash[0][1][smt][kg][ 0 + sr][0] = lv0;
    *(uint4*)&Ash[0][1][smt][kg][32 + sr][0] = lv1;
  }
#pragma unroll
  for (int i = 0; i < 4; ++i)
    *(float4*)(ar + i * 4) = *(const float4*)(ap + 128 + i * 4);

  short8 b[2][2];
  b[0][0] = *(const short8*)(ph);
  b[0][1] = *(const short8*)(pl);
  b[1][0] = *(const short8*)(ph + 512);
  b[1][1] = *(const short8*)(pl + 512);

  // one k-half = 16 chunks into a dedicated acc pair (preserves R7 summation)
  auto half_loop = [&](int cbeg, f32x16& acc0, f32x16& acc1) {
    for (int c = cbeg; c < cbeg + 16; ++c) {
      const int buf = c & 1;
      // T4: cross-wave hazard is LDS-only. Drain lgkm (my staging ds_writes),
      // raw barrier, NO vmcnt drain -> A/B prefetch stays in flight across it.
      asm volatile("s_waitcnt lgkmcnt(0)" ::: "memory");
      __builtin_amdgcn_s_barrier();
      asm volatile("" ::: "memory");   // no hoisting of buf reads above barrier

#pragma unroll
      for (int ks = 0; ks < 8; ++ks) {
        const int gs = c * 8 + ks;
        short8 Bh = b[gs & 1][0], Bl = b[gs & 1][1];
        const size_t gp = (size_t)((gs + 2 < 256) ? gs + 2 : gs) * 512;
        b[gs & 1][0] = *(const short8*)(ph + gp);
        b[gs & 1][1] = *(const short8*)(pl + gp);

        short8 a0h = *(const short8*)&Ash[buf][0][0][ks][l][0];
        short8 a0l = *(const short8*)&Ash[buf][1][0][ks][l][0];
        short8 a1h = *(const short8*)&Ash[buf][0][1][ks][l][0];
        short8 a1l = *(const short8*)&Ash[buf][1][1][ks][l][0];

        __builtin_amdgcn_s_setprio(1);
        acc0 = mfma32(a0h, Bh, acc0);  acc1 = mfma32(a1h, Bh, acc1);
        acc0 = mfma32(a0l, Bh, acc0);  acc1 = mfma32(a1l, Bh, acc1);
        acc0 = mfma32(a0h, Bl, acc0);  acc1 = mfma32(a1h, Bl, acc1);
        __builtin_amdgcn_s_setprio(0);
      }

      if (c < 31) {
        // stage chunk c+1 (regs landed a full chunk ago) into the other buffer
        {
          uint4 hv0, lv0, hv1, lv1;
          split8(ar,     hv0, lv0);
          split8(ar + 8, hv1, lv1);
          *(uint4*)&Ash[buf ^ 1][0][smt][kg][ 0 + sr][0] = hv0;
          *(uint4*)&Ash[buf ^ 1][0][smt][kg][32 + sr][0] = hv1;
          *(uint4*)&Ash[buf ^ 1][1][smt][kg][ 0 + sr][0] = lv0;
          *(uint4*)&Ash[buf ^ 1][1][smt][kg][32 + sr][0] = lv1;
        }
        // issue chunk c+2 loads: a full chunk of compute to land
        if (c + 2 < 32) {
#pragma unroll
          for (int i = 0; i < 4; ++i)
            *(float4*)(ar + i * 4) = *(const float4*)(ap + (size_t)(c + 2) * 128 + i * 4);
        }
      }
    }
  };
  half_loop(0,  accA0, accA1);
  half_loop(16, accB0, accB1);

  // ---- epilogue: acc -> LDS, coalesced classify store, in-block top-8 ------------
  __syncthreads();                         // all Ash reads done; safe to reuse
  float* Cl = (float*)Ash;                 // [64][256] f32 = 64 KB

  // 32x32 C/D layout: col=lane&31, row=(r&3)+8*(r>>2)+4*(lane>>5)
  const int rbl = 4 * (l >> 5);
  const int cb  = w * 32 + (l & 31);
#pragma unroll
  for (int r = 0; r < 16; ++r) {
    const int rl = rbl + (r & 3) + 8 * (r >> 2);     // 0..31
    Cl[(size_t)rl * NE + cb]        = accA0[r] + accB0[r];
    Cl[(size_t)(rl + 32) * NE + cb] = accA1[r] + accB1[r];
  }
  __syncthreads();

  // wave w handles rows w*8 .. w*8+7; per row: lane owns 4 scores
  const float4 b4 = *(const float4*)(bias + l * 4);
  for (int i = 0; i < 8; ++i) {
    const int rl  = w * 8 + i;
    const int tok = band * 64 + rl;
    float4 c4 = *(const float4*)&Cl[(size_t)rl * NE + l * 4];
    *(float4*)(classify + (size_t)tok * NE + l * 4) = c4;   // coalesced, once
    float v0 = c4.x, v1 = c4.y, v2 = c4.z, v3 = c4.w;

    float mx = fmaxf(fmaxf(v0, v1), fmaxf(v2, v3));
#pragma unroll
    for (int off = 32; off >= 1; off >>= 1) mx = fmaxf(mx, __shfl_xor(mx, off));

    float e0 = __expf(v0 - mx), e1 = __expf(v1 - mx);
    float e2 = __expf(v2 - mx), e3 = __expf(v3 - mx);
    float sum = e0 + e1 + e2 + e3;
#pragma unroll
    for (int off = 32; off >= 1; off >>= 1) sum += __shfl_xor(sum, off);

    float sc0 = e0 / sum, sc1 = e1 / sum, sc2 = e2 / sum, sc3 = e3 / sum;
    float ch0 = sc0 + b4.x, ch1 = sc1 + b4.y, ch2 = sc2 + b4.z, ch3 = sc3 + b4.w;

#pragma unroll
    for (int t = 0; t < TOPK_N; ++t) {
      float bv = ch0; int bi = 0; float bs = sc0;
      if (ch1 > bv) { bv = ch1; bi = 1; bs = sc1; }
      if (ch2 > bv) { bv = ch2; bi = 2; bs = sc2; }
      if (ch3 > bv) { bv = ch3; bi = 3; bs = sc3; }
      int be = l * 4 + bi;
#pragma unroll
      for (int off = 32; off >= 1; off >>= 1) {
        float ov = __shfl_xor(bv, off);
        int   oe = __shfl_xor(be, off);
        float os = __shfl_xor(bs, off);
        if (ov > bv || (ov == bv && oe < be)) { bv = ov; be = oe; bs = os; }
      }
      if (l == 0) {
        wOut[(size_t)tok * TOPK_N + t] = bs * 1.5f;
        iOut[(size_t)tok * TOPK_N + t] = (float)be;
      }
      bool own = (be >> 2) == l;
      int  lb  = be & 3;
      if (own && lb == 0) ch0 = -INFINITY;
      if (own && lb == 1) ch1 = -INFINITY;
      if (own && lb == 2) ch2 = -INFINITY;
      if (own && lb == 3) ch3 = -INFINITY;
    }
  }
}

extern "C" void kernel_launch(void* const* d_in, const int* in_sizes, int n_in,
                              void* d_out, int out_size, void* d_ws, size_t ws_size,
                              hipStream_t stream) {
  const float* hs   = (const float*)d_in[0];   // [16384, 4096] f32
  const float* W    = (const float*)d_in[1];   // [256, 4096]   f32
  const float* bias = (const float*)d_in[2];   // [256]         f32

  float* out      = (float*)d_out;
  float* classify = out;                               // 16384*256
  float* wOut     = out + (size_t)T_TOK * NE;          // 16384*8
  float* iOut     = wOut + (size_t)T_TOK * TOPK_N;     // 16384*8

  unsigned short* Whp = (unsigned short*)d_ws;         // 2 MB packed hi
  unsigned short* Wlp = Whp + (size_t)NE * DIM;        // 2 MB packed lo

  convert_w_kernel<<<(NE * DIM / 8) / 256, 256, 0, stream>>>(W, Whp, Wlp);
  router_fused<<<256, 512, 0, stream>>>(hs, Whp, Wlp, bias,
                                        classify, wOut, iOut);
}